// Round 5
// baseline (2930.579 us; speedup 1.0000x reference)
//
#include <hip/hip_runtime.h>
#include <hip/hip_bf16.h>

typedef unsigned short ushort_t;

#define NDIM 256

__device__ __forceinline__ float bf2f(ushort_t u) {
    union { unsigned int i; float f; } x; x.i = ((unsigned int)u) << 16; return x.f;
}
// round-to-nearest-even f32 -> bf16
__device__ __forceinline__ ushort_t f2bf(float f) {
    unsigned int u = __float_as_uint(f);
    unsigned int r = (u + 0x7FFFu + ((u >> 16) & 1u)) >> 16;
    return (ushort_t)r;
}
// load float input element i, honoring runtime dtype flag (1 = bf16, 0 = f32)
__device__ __forceinline__ float ldf(const void* p, int i, int isbf) {
    return isbf ? bf2f(((const ushort_t*)p)[i]) : ((const float*)p)[i];
}
__device__ __forceinline__ int get_idx(const void* arr, int i, int is64) {
    if (is64) return (int)((const long long*)arr)[i];
    return ((const int*)arr)[i];
}

// ---- probe m's words: bf16 data has low-u16 bf16-exponent concentrated ----
__global__ void k_probe(const unsigned int* __restrict__ w, int* __restrict__ flag) {
    __shared__ int cnt_in;
    if (threadIdx.x == 0) cnt_in = 0;
    __syncthreads();
    int local = 0;
    for (int i = threadIdx.x; i < 4096; i += blockDim.x) {
        unsigned int e = (w[i] >> 7) & 0xFFu;
        if (e >= 110u && e <= 135u) local++;
    }
    atomicAdd(&cnt_in, local);
    __syncthreads();
    if (threadIdx.x == 0) *flag = (cnt_in >= 2048) ? 1 : 0;
}

// ---- probe index width: int64 (<2^31 values) has all odd 32-bit words zero ----
__global__ void k_detect(const unsigned int* __restrict__ rows_w, int nnz, int* __restrict__ flag) {
    __shared__ int nz;
    if (threadIdx.x == 0) nz = 0;
    __syncthreads();
    int samples = min(nnz / 2, 4096);
    for (int i = threadIdx.x; i < samples; i += blockDim.x) {
        if (rows_w[2 * i + 1] != 0u) atomicAdd(&nz, 1);
    }
    __syncthreads();
    if (threadIdx.x == 0) *flag = (nz == 0) ? 1 : 0;
}

// ---- m -> Hb (canonical bf16) ----
__global__ void k_cvt_m(const void* __restrict__ src, ushort_t* __restrict__ dst, int n,
                        const int* __restrict__ flag) {
    int i = blockIdx.x * blockDim.x + threadIdx.x;
    if (i >= n) return;
    int isbf = *flag;
    dst[i] = isbf ? ((const ushort_t*)src)[i] : f2bf(((const float*)src)[i]);
}

// ---- combined bias bn+bs -> f32 ----
__global__ void k_bias(const void* __restrict__ bn, const void* __restrict__ bs,
                       float* __restrict__ bc, int n, const int* __restrict__ flag) {
    int i = blockIdx.x * blockDim.x + threadIdx.x;
    if (i >= n) return;
    int isbf = *flag;
    bc[i] = ldf(bn, i, isbf) + ldf(bs, i, isbf);
}

// ---- plain weight transpose: Wt[i][k][n] = W[i][n][k], f32 out ----
__global__ void k_wtrans(const void* __restrict__ Wn, const void* __restrict__ Ws,
                         float* __restrict__ WtN, float* __restrict__ WtS,
                         int total, const int* __restrict__ flag) {
    int t = blockIdx.x * blockDim.x + threadIdx.x;
    if (t >= total) return;
    int isbf = *flag;
    int i   = t >> 16;          // / 65536
    int rem = t & 65535;
    int k = rem >> 8;
    int n = rem & 255;
    WtN[t] = ldf(Wn, i * 65536 + n * 256 + k, isbf);
    WtS[t] = ldf(Ws, i * 65536 + n * 256 + k, isbf);
}

// ---- CSR build ----
__global__ void k_hist(const void* __restrict__ rows, int* __restrict__ cnt, int nnz,
                       const int* __restrict__ flag) {
    int is64 = *flag;
    int i = blockIdx.x * blockDim.x + threadIdx.x;
    if (i < nnz) atomicAdd(&cnt[get_idx(rows, i, is64)], 1);
}

__global__ void k_chunksum(const int* __restrict__ cnt, int* __restrict__ csum, int n) {
    __shared__ int s[256];
    int i = blockIdx.x * 256 + threadIdx.x;
    int v = (i < n) ? cnt[i] : 0;
    s[threadIdx.x] = v;
    __syncthreads();
    for (int off = 128; off > 0; off >>= 1) {
        if (threadIdx.x < off) s[threadIdx.x] += s[threadIdx.x + off];
        __syncthreads();
    }
    if (threadIdx.x == 0) csum[blockIdx.x] = s[0];
}

__global__ void k_scanchunks(const int* __restrict__ csum, int* __restrict__ coff, int nchunks) {
    __shared__ int a[512], b[512];
    int t = threadIdx.x;
    int v = (t < nchunks) ? csum[t] : 0;
    a[t] = v;
    __syncthreads();
    int* src = a; int* dst = b;
    for (int off = 1; off < 512; off <<= 1) {
        dst[t] = src[t] + ((t >= off) ? src[t - off] : 0);
        __syncthreads();
        int* tmp = src; src = dst; dst = tmp;
    }
    if (t < nchunks) coff[t] = src[t] - v;   // exclusive
}

__global__ void k_scanwrite(const int* __restrict__ cnt, const int* __restrict__ coff,
                            int* __restrict__ row_start, int* __restrict__ row_cur,
                            int n, int nnz) {
    __shared__ int a[256], b[256];
    int t = threadIdx.x;
    int i = blockIdx.x * 256 + t;
    int v = (i < n) ? cnt[i] : 0;
    a[t] = v;
    __syncthreads();
    int* src = a; int* dst = b;
    for (int off = 1; off < 256; off <<= 1) {
        dst[t] = src[t] + ((t >= off) ? src[t - off] : 0);
        __syncthreads();
        int* tmp = src; src = dst; dst = tmp;
    }
    int excl = src[t] - v + coff[blockIdx.x];
    if (i < n) { row_start[i] = excl; row_cur[i] = excl; }
    if (i == n) row_start[n] = nnz;
}

__global__ void k_scatter(const void* __restrict__ rows, const void* __restrict__ cols,
                          const void* __restrict__ vals, int* __restrict__ row_cur,
                          int2* __restrict__ edata, int nnz,
                          const int* __restrict__ iflag, const int* __restrict__ fflag) {
    int is64 = *iflag;
    int isbf = *fflag;
    int i = blockIdx.x * blockDim.x + threadIdx.x;
    if (i >= nnz) return;
    int r = get_idx(rows, i, is64);
    int c = get_idx(cols, i, is64);
    float v = ldf(vals, i, isbf);
    int p = atomicAdd(&row_cur[r], 1);
    edata[p] = make_int2(c, __float_as_int(v));
}

// ---- SpMM: one wave per row, fp32 accumulate, bf16 in/out ----
__global__ void k_spmm(const ushort_t* __restrict__ hb, const int* __restrict__ row_start,
                       const int2* __restrict__ edata, ushort_t* __restrict__ hn, int n) {
    int wid = (blockIdx.x * blockDim.x + threadIdx.x) >> 6;
    if (wid >= n) return;
    wid = __builtin_amdgcn_readfirstlane(wid);
    int lane = threadIdx.x & 63;
    int e0 = row_start[wid];
    int e1 = row_start[wid + 1];
    float a0 = 0.f, a1 = 0.f, a2 = 0.f, a3 = 0.f;
    int off = lane * 4;
    for (int e = e0; e < e1; ++e) {
        int2 ed = edata[e];
        float v = __int_as_float(ed.y);
        ushort4 h = *reinterpret_cast<const ushort4*>(hb + (((long)ed.x) << 8) + off);
        a0 += bf2f(h.x) * v;
        a1 += bf2f(h.y) * v;
        a2 += bf2f(h.z) * v;
        a3 += bf2f(h.w) * v;
    }
    ushort4 o;
    o.x = f2bf(a0); o.y = f2bf(a1); o.z = f2bf(a2); o.w = f2bf(a3);
    *reinterpret_cast<ushort4*>(hn + (((long)wid) << 8) + off) = o;
}

// ---- VALU GEMM: out[r][n] = act( sum_k Hn[r][k]*WtN[k][n] + Hb[r][k]*WtS[k][n] + bc[n] )
// block = 256 threads; 16 rows x 256 cols per block; thread = one col, 16 rows.
// writeF32: last hop writes f32 to d_out (reference output dtype is float32!);
// intermediate hops write bf16 into Hb.
__global__ __launch_bounds__(256) void k_gemm_valu(
        const ushort_t* __restrict__ hn, const ushort_t* __restrict__ hb,
        const float* __restrict__ wtn, const float* __restrict__ wts,
        const float* __restrict__ bc, void* __restrict__ dst,
        int applyElu, int writeF32, int nvalid) {
    __shared__ float hnS[16][256];
    __shared__ float hbS[16][256];
    int t = threadIdx.x;
    int rbase = blockIdx.x * 16;
    for (int v = t; v < 4096; v += 256) {
        int r = v >> 8, c = v & 255;
        int row = rbase + r;
        if (row < nvalid) {
            hnS[r][c] = bf2f(hn[(((long)row) << 8) + c]);
            hbS[r][c] = bf2f(hb[(((long)row) << 8) + c]);
        } else {
            hnS[r][c] = 0.f;
            hbS[r][c] = 0.f;
        }
    }
    __syncthreads();

    int n = t;   // output column
    float acc[16];
    #pragma unroll
    for (int r = 0; r < 16; ++r) acc[r] = 0.f;

    for (int k = 0; k < 256; k += 4) {
        float w10 = wtn[((k + 0) << 8) + n];
        float w11 = wtn[((k + 1) << 8) + n];
        float w12 = wtn[((k + 2) << 8) + n];
        float w13 = wtn[((k + 3) << 8) + n];
        float w20 = wts[((k + 0) << 8) + n];
        float w21 = wts[((k + 1) << 8) + n];
        float w22 = wts[((k + 2) << 8) + n];
        float w23 = wts[((k + 3) << 8) + n];
        #pragma unroll
        for (int r = 0; r < 16; ++r) {
            float4 a = *reinterpret_cast<const float4*>(&hnS[r][k]);
            float4 b = *reinterpret_cast<const float4*>(&hbS[r][k]);
            acc[r] += a.x * w10 + a.y * w11 + a.z * w12 + a.w * w13
                    + b.x * w20 + b.y * w21 + b.z * w22 + b.w * w23;
        }
    }

    float bias = bc[n];
    #pragma unroll
    for (int r = 0; r < 16; ++r) {
        int row = rbase + r;
        if (row < nvalid) {
            float v = acc[r] + bias;
            if (applyElu) v = (v > 0.f) ? v : expm1f(v);
            if (writeF32) ((float*)dst)[(((long)row) << 8) + n] = v;
            else          ((ushort_t*)dst)[(((long)row) << 8) + n] = f2bf(v);
        }
    }
}

extern "C" void kernel_launch(void* const* d_in, const int* in_sizes, int n_in,
                              void* d_out, int out_size, void* d_ws, size_t ws_size,
                              hipStream_t stream) {
    const void* m    = d_in[0];
    const void* vals = d_in[1];
    const void* Wn   = d_in[2];
    const void* bn   = d_in[3];
    const void* Ws   = d_in[4];
    const void* bs   = d_in[5];
    const void* rows = d_in[6];
    const void* cols = d_in[7];

    const int N    = in_sizes[0] / NDIM;      // 100000
    const int nnz  = in_sizes[1];             // 3200000
    const int hops = in_sizes[3] / NDIM;      // 3
    const size_t mpad = ((size_t)N + 63) & ~(size_t)63;

    char* p = (char*)d_ws;
    ushort_t* Hb = (ushort_t*)p; p += mpad * NDIM * 2;
    ushort_t* Hn = (ushort_t*)p; p += mpad * NDIM * 2;
    float* WtN     = (float*)p; p += (size_t)hops * 65536 * 4;
    float* WtS     = (float*)p; p += (size_t)hops * 65536 * 4;
    float* Bc      = (float*)p; p += (size_t)hops * 256 * 4;
    int* cnt       = (int*)p; p += ((size_t)N + 256) * 4;
    int* row_start = (int*)p; p += ((size_t)N + 256) * 4;
    int* row_cur   = (int*)p; p += ((size_t)N + 256) * 4;
    int* csum      = (int*)p; p += 512 * 4;
    int* coff      = (int*)p; p += 512 * 4;
    int* iflag     = (int*)p; p += 64;
    int* fflag     = (int*)p; p += 64;
    p = (char*)(((uintptr_t)p + 15) & ~(uintptr_t)15);
    int2* edata = (int2*)p; p += (size_t)nnz * 8;

    hipMemsetAsync(cnt, 0, (size_t)(N + 1) * sizeof(int), stream);

    k_probe<<<1, 256, 0, stream>>>((const unsigned int*)m, fflag);
    k_detect<<<1, 256, 0, stream>>>((const unsigned int*)rows, nnz, iflag);

    int nm = N * NDIM;
    k_cvt_m<<<(nm + 255) / 256, 256, 0, stream>>>(m, Hb, nm, fflag);

    int nb = hops * 256;
    k_bias<<<(nb + 255) / 256, 256, 0, stream>>>(bn, bs, Bc, nb, fflag);

    int wtotal = hops * 65536;
    k_wtrans<<<(wtotal + 255) / 256, 256, 0, stream>>>(Wn, Ws, WtN, WtS, wtotal, fflag);

    k_hist<<<(nnz + 255) / 256, 256, 0, stream>>>(rows, cnt, nnz, iflag);

    int nchunks = (N + 255) / 256;
    k_chunksum<<<nchunks, 256, 0, stream>>>(cnt, csum, N);
    k_scanchunks<<<1, 512, 0, stream>>>(csum, coff, nchunks);
    k_scanwrite<<<nchunks, 256, 0, stream>>>(cnt, coff, row_start, row_cur, N, nnz);
    k_scatter<<<(nnz + 255) / 256, 256, 0, stream>>>(rows, cols, vals, row_cur, edata, nnz, iflag, fflag);

    int spmm_blocks = (N + 3) / 4;
    int gemm_blocks = (N + 15) / 16;

    for (int hop = 0; hop < hops; ++hop) {
        k_spmm<<<spmm_blocks, 256, 0, stream>>>(Hb, row_start, edata, Hn, N);
        int last = (hop == hops - 1);
        void* dst = last ? d_out : (void*)Hb;
        k_gemm_valu<<<gemm_blocks, 256, 0, stream>>>(
            Hn, Hb,
            WtN + (size_t)hop * 65536, WtS + (size_t)hop * 65536,
            Bc + (size_t)hop * 256,
            dst, last ? 0 : 1, last ? 1 : 0, N);
    }
}